// Round 1
// baseline (568.596 us; speedup 1.0000x reference)
//
#include <hip/hip_runtime.h>

typedef unsigned short u16;
typedef float f32x4 __attribute__((ext_vector_type(4)));
typedef unsigned int uint4v __attribute__((ext_vector_type(4)));

#define BB 64
#define TT 2048
#define THEAD 2046
#define DD 1024
#define PP 512

// ---------- helpers ----------
__device__ __forceinline__ u16 f2bf(float f) {
  unsigned int u = __float_as_uint(f);
  return (u16)((u + 0x7fffu + ((u >> 16) & 1u)) >> 16);
}
__device__ __forceinline__ float bf2f(u16 h) {
  return __uint_as_float(((unsigned int)h) << 16);
}
__device__ __forceinline__ float tanh_fast(float x) {
  float cx = fminf(fmaxf(x, -15.f), 15.f);
  float e = __expf(2.f * cx);
  return (e - 1.f) * __builtin_amdgcn_rcpf(e + 1.f);
}
__device__ __forceinline__ void cp16(const void* g, void* l) {
  __builtin_amdgcn_global_load_lds(
      (const __attribute__((address_space(1))) unsigned int*)g,
      (__attribute__((address_space(3))) unsigned int*)l, 16, 0, 0);
}
__device__ __forceinline__ void mfma16(f32x4& c, uint4v a, uint4v b) {
  asm("v_mfma_f32_16x16x32_bf16 %0, %1, %2, %0" : "+v"(c) : "v"(a), "v"(b));
}

// ---------- kernel 1: transpose+convert weights to bf16 ----------
// phT[512][1024], w0T[512][512], w1T[512][512]  (all [n][k], bf16)
__global__ __launch_bounds__(256) void cvt_k(const float* __restrict__ ph,
                                             const float* __restrict__ hw,
                                             u16* __restrict__ phT,
                                             u16* __restrict__ w0T,
                                             u16* __restrict__ w1T) {
  __shared__ float tl[32][33];
  const int bid = blockIdx.x, tid = threadIdx.x;
  const float* src;
  u16* dst;
  int SC, SR, r0, c0;
  if (bid < 512) {  // proj_head 1024x512 -> phT 512x1024
    int tr = bid >> 4, tc = bid & 15;
    src = ph; SC = 512; dst = phT; SR = 1024; r0 = tr * 32; c0 = tc * 32;
  } else if (bid < 768) {  // W0 512x512
    int i = bid - 512; int tr = i >> 4, tc = i & 15;
    src = hw; SC = 512; dst = w0T; SR = 512; r0 = tr * 32; c0 = tc * 32;
  } else {  // W1 512x512
    int i = bid - 768; int tr = i >> 4, tc = i & 15;
    src = hw + 512 * 512; SC = 512; dst = w1T; SR = 512; r0 = tr * 32; c0 = tc * 32;
  }
  for (int i = tid; i < 1024; i += 256) {
    int r = i >> 5, c = i & 31;
    tl[r][c] = src[(size_t)(r0 + r) * SC + c0 + c];
  }
  __syncthreads();
  for (int i = tid; i < 1024; i += 256) {
    int r = i >> 5, c = i & 31;  // out row = c0+r, out col = r0+c
    dst[(size_t)(c0 + r) * SR + r0 + c] = f2bf(tl[c][r]);
  }
}

// ---------- kernel 2: fp32 bias = prep@proj_prep + child@proj_child ----------
__global__ __launch_bounds__(256) void bias_k(const float* __restrict__ x,
                                              const float* __restrict__ pp,
                                              const float* __restrict__ pc,
                                              float* __restrict__ bias) {
  const int b = blockIdx.x >> 3, pt = blockIdx.x & 7, tid = threadIdx.x;
  __shared__ float sprep[DD], schild[DD];
  __shared__ float red[4][64];
  for (int i = tid; i < DD; i += 256) {
    sprep[i] = x[((size_t)b * TT + (TT - 2)) * DD + i];
    schild[i] = x[((size_t)b * TT + (TT - 1)) * DD + i];
  }
  __syncthreads();
  const int pl = tid & 63, kq = tid >> 6;
  const int p = pt * 64 + pl;
  float s = 0.f;
  for (int k = kq * 256; k < kq * 256 + 256; ++k)
    s += sprep[k] * pp[(size_t)k * PP + p] + schild[k] * pc[(size_t)k * PP + p];
  red[kq][pl] = s;
  __syncthreads();
  if (tid < 64)
    bias[(size_t)b * PP + pt * 64 + tid] =
        red[0][tid] + red[1][tid] + red[2][tid] + red[3][tid];
}

// ---------- kernel 3: fused main ----------
// per block: 64 t-rows of one batch; full P=512 width.
// stage A: tanh(X@Ph + bias) -> Ct ; stage B/C: tanh(Ct@Wl) -> Ct ;
// stage D: scores=Ct@scorer, exp, mask, write, partial sums.
__global__ __launch_bounds__(512) void fused_main(
    const float* __restrict__ x, const u16* __restrict__ phT,
    const u16* __restrict__ w0T, const u16* __restrict__ w1T,
    const float* __restrict__ bias, const float* __restrict__ scorer,
    const int* __restrict__ mask, float* __restrict__ out,
    float* __restrict__ partials) {
  __shared__ u16 Bt[PP * 64];      // weight slab [512][64], XOR-swizzled
  __shared__ u16 At[64 * 64];      // X slab [64][64], XOR-swizzled
  __shared__ u16 Ct[64 * 536];     // composed tile [64][512] (+pad 24)
  __shared__ float ssc[PP];
  __shared__ float sred[64];

  const int tile = blockIdx.x, b = blockIdx.y;
  const int tid = threadIdx.x;
  const int lane = tid & 63, wid = tid >> 6;
  const int wm = wid >> 2, wn = wid & 3;   // 2x4 wave grid -> 32x128 per wave
  const int lr = lane & 15, kg = lane >> 4;
  const int sub = lane >> 3, cb = lane & 7;
  const int scol = ((cb ^ sub) << 3);      // pre-swizzled source col (elems)

  ssc[tid] = scorer[tid];

  f32x4 acc[2][8];
#pragma unroll
  for (int m = 0; m < 2; ++m)
#pragma unroll
    for (int n = 0; n < 8; ++n) acc[m][n] = (f32x4){0.f, 0.f, 0.f, 0.f};

  const int r_st = tid >> 3, kp = tid & 7;
  const size_t xrow = ((size_t)b * TT + tile * 64 + r_st) * DD;

  // ---- stage A: K=1024, BK=64 ----
  for (int ks = 0; ks < 16; ++ks) {
    const int k0 = ks << 6;
#pragma unroll
    for (int i = 0; i < 8; ++i) {
      const int r = (wid << 6) + (i << 3) + sub;
      cp16(phT + ((size_t)r << 10) + k0 + scol, &Bt[((wid << 6) + (i << 3)) << 6]);
    }
    {  // X fp32 -> bf16 -> At (swizzled write)
      const float4* src = (const float4*)(x + xrow + k0 + (kp << 3));
      float4 v0 = src[0], v1 = src[1];
      uint4 pk;
      pk.x = f2bf(v0.x) | ((unsigned)f2bf(v0.y) << 16);
      pk.y = f2bf(v0.z) | ((unsigned)f2bf(v0.w) << 16);
      pk.z = f2bf(v1.x) | ((unsigned)f2bf(v1.y) << 16);
      pk.w = f2bf(v1.z) | ((unsigned)f2bf(v1.w) << 16);
      *(uint4*)&At[(r_st << 6) + ((kp ^ (r_st & 7)) << 3)] = pk;
    }
    __syncthreads();
#pragma unroll
    for (int kc = 0; kc < 2; ++kc) {
      uint4v af[2], bfr[8];
#pragma unroll
      for (int mr = 0; mr < 2; ++mr) {
        const int r = (wm << 5) + (mr << 4) + lr;
        const int bo = ((kc << 6) + (kg << 4)) ^ ((r & 7) << 4);
        af[mr] = *(const uint4v*)((const char*)At + (r << 7) + bo);
      }
#pragma unroll
      for (int nr = 0; nr < 8; ++nr) {
        const int n = (wn << 7) + (nr << 4) + lr;
        const int bo = ((kc << 6) + (kg << 4)) ^ ((n & 7) << 4);
        bfr[nr] = *(const uint4v*)((const char*)Bt + (n << 7) + bo);
      }
#pragma unroll
      for (int mr = 0; mr < 2; ++mr)
#pragma unroll
        for (int nr = 0; nr < 8; ++nr) mfma16(acc[mr][nr], af[mr], bfr[nr]);
    }
    __syncthreads();
  }
  // epilogue A: + fp32 bias, tanh, -> Ct (bf16)
  {
    float bv[8];
#pragma unroll
    for (int nr = 0; nr < 8; ++nr)
      bv[nr] = bias[(b << 9) + (wn << 7) + (nr << 4) + lr];
#pragma unroll
    for (int mr = 0; mr < 2; ++mr)
#pragma unroll
      for (int nr = 0; nr < 8; ++nr) {
        const int c = (wn << 7) + (nr << 4) + lr;
        const int r0 = (wm << 5) + (mr << 4) + (kg << 2);
#pragma unroll
        for (int j = 0; j < 4; ++j)
          Ct[(r0 + j) * 536 + c] = f2bf(tanh_fast(acc[mr][nr][j] + bv[nr]));
      }
  }
  __syncthreads();

  // ---- stages B and C: K=512, BK=64 ----
  for (int layer = 0; layer < 2; ++layer) {
    const u16* wT = layer ? w1T : w0T;
#pragma unroll
    for (int m = 0; m < 2; ++m)
#pragma unroll
      for (int n = 0; n < 8; ++n) acc[m][n] = (f32x4){0.f, 0.f, 0.f, 0.f};
    for (int ks = 0; ks < 8; ++ks) {
      const int k0 = ks << 6;
#pragma unroll
      for (int i = 0; i < 8; ++i) {
        const int r = (wid << 6) + (i << 3) + sub;
        cp16(wT + ((size_t)r << 9) + k0 + scol, &Bt[((wid << 6) + (i << 3)) << 6]);
      }
      __syncthreads();
#pragma unroll
      for (int kc = 0; kc < 2; ++kc) {
        uint4v af[2], bfr[8];
#pragma unroll
        for (int mr = 0; mr < 2; ++mr) {
          const int r = (wm << 5) + (mr << 4) + lr;
          af[mr] = *(const uint4v*)&Ct[r * 536 + k0 + (kc << 5) + (kg << 3)];
        }
#pragma unroll
        for (int nr = 0; nr < 8; ++nr) {
          const int n = (wn << 7) + (nr << 4) + lr;
          const int bo = ((kc << 6) + (kg << 4)) ^ ((n & 7) << 4);
          bfr[nr] = *(const uint4v*)((const char*)Bt + (n << 7) + bo);
        }
#pragma unroll
        for (int mr = 0; mr < 2; ++mr)
#pragma unroll
          for (int nr = 0; nr < 8; ++nr) mfma16(acc[mr][nr], af[mr], bfr[nr]);
      }
      __syncthreads();
    }
#pragma unroll
    for (int mr = 0; mr < 2; ++mr)
#pragma unroll
      for (int nr = 0; nr < 8; ++nr) {
        const int c = (wn << 7) + (nr << 4) + lr;
        const int r0 = (wm << 5) + (mr << 4) + (kg << 2);
#pragma unroll
        for (int j = 0; j < 4; ++j)
          Ct[(r0 + j) * 536 + c] = f2bf(tanh_fast(acc[mr][nr][j]));
      }
    __syncthreads();
  }

  // ---- stage D: scores -> exp -> mask -> out, block partial sum ----
  {
    const int r = tid >> 3, j = tid & 7;
    const int p0 = j << 6;
    float s = 0.f;
#pragma unroll 8
    for (int p = 0; p < 64; ++p) s += bf2f(Ct[r * 536 + p0 + p]) * ssc[p0 + p];
    s += __shfl_down(s, 4, 8);
    s += __shfl_down(s, 2, 8);
    s += __shfl_down(s, 1, 8);
    if (j == 0) {
      const int tg = (tile << 6) + r;
      float e = 0.f;
      if (tg < THEAD && mask[(size_t)b * TT + tg] != 0) e = __expf(s);
      if (tg < THEAD) out[(size_t)b * THEAD + tg] = e;
      sred[r] = e;
    }
    __syncthreads();
    if (tid < 64) {
      float v = sred[tid];
      v += __shfl_down(v, 32);
      v += __shfl_down(v, 16);
      v += __shfl_down(v, 8);
      v += __shfl_down(v, 4);
      v += __shfl_down(v, 2);
      v += __shfl_down(v, 1);
      if (tid == 0) partials[(b << 5) + tile] = v;
    }
  }
}

// ---------- kernel 4: normalize ----------
__global__ __launch_bounds__(256) void norm_k(float* __restrict__ out,
                                              const float* __restrict__ partials) {
  const int b = blockIdx.y, j = blockIdx.x, tid = threadIdx.x;
  __shared__ float sinv;
  if (tid < 32) {
    float v = partials[(b << 5) + tid];
    v += __shfl_down(v, 16, 32);
    v += __shfl_down(v, 8, 32);
    v += __shfl_down(v, 4, 32);
    v += __shfl_down(v, 2, 32);
    v += __shfl_down(v, 1, 32);
    if (tid == 0) sinv = 1.f / (v + 1e-7f);
  }
  __syncthreads();
  const int t = (j << 8) + tid;
  if (t < THEAD) out[(size_t)b * THEAD + t] *= sinv;
}

extern "C" void kernel_launch(void* const* d_in, const int* in_sizes, int n_in,
                              void* d_out, int out_size, void* d_ws, size_t ws_size,
                              hipStream_t stream) {
  const float* x  = (const float*)d_in[0];
  const float* ph = (const float*)d_in[1];
  const float* pp = (const float*)d_in[2];
  const float* pc = (const float*)d_in[3];
  const float* hw = (const float*)d_in[4];
  const float* sc = (const float*)d_in[5];
  const int* mask = (const int*)d_in[6];
  float* out = (float*)d_out;

  char* ws = (char*)d_ws;
  u16* phT = (u16*)ws;                               // 1 MiB
  u16* w0T = (u16*)(ws + (1 << 20));                 // 512 KiB
  u16* w1T = (u16*)(ws + (1 << 20) + (1 << 19));     // 512 KiB
  float* biasb = (float*)(ws + (1 << 21));           // 128 KiB
  float* partials = (float*)(ws + (1 << 21) + 131072);  // 8 KiB

  cvt_k<<<1024, 256, 0, stream>>>(ph, hw, phT, w0T, w1T);
  bias_k<<<512, 256, 0, stream>>>(x, pp, pc, biasb);
  fused_main<<<dim3(32, 64), 512, 0, stream>>>(x, phT, w0T, w1T, biasb, sc,
                                               mask, out, partials);
  norm_k<<<dim3(8, 64), 256, 0, stream>>>(out, partials);
}